// Round 3
// baseline (230.321 us; speedup 1.0000x reference)
//
#include <hip/hip_runtime.h>
#include <math.h>

// Gaussian blur 21x21, sigma=5, depthwise over [B=32, C=3, H=512, W=512] fp32,
// reflect padding, separable, fused single kernel.
//
// R3: LDS-pipe attack.
//  - s_in stride 88 (pad +4), s_h stride 68 (pad +4): break mod-32 row banking.
//  - stage1: interior-x blocks load float4 global (window x0-12..x0+75, aligned)
//            -> 29 b128 LDS writes/block (was 110 b32 loads+writes).
//  - stage2: 8 outputs/thread: 8 b128 reads + 2 b128 writes per 8 outputs.
//  - stage3: wave-per-16-row-strip, lane=x, b32 sliding column reads:
//            wave-uniform row + lane offset -> 2 lanes/bank -> conflict-FREE.
// LDS 84*88*4 + 84*68*4 = 52.4 KB -> 3 blocks/CU.

#define KS   21
#define PAD  10
#define TILE 64
#define LH   (TILE + 2 * PAD)   // 84 rows in LDS
#define SW_IN 88                // s_in row stride (cols 0..87 <-> gx = x0-12 .. x0+75)
#define SW_H  68                // s_h row stride
#define IMG_H 512
#define IMG_W 512
#define NTHREADS 256

__global__ __launch_bounds__(NTHREADS) void gauss_blur_kernel(
    const float* __restrict__ in, float* __restrict__ out)
{
    __shared__ __align__(16) float s_in[LH * SW_IN];  // 84*88*4 = 29568 B
    __shared__ __align__(16) float s_h [LH * SW_H];   // 84*68*4 = 22848 B

    // Normalized 1-D Gaussian (sum(outer(g,g)) = sum(g)^2 -> 1-D normalization
    // reproduces the reference's 2-D normalization).
    float w[KS];
    {
        float s = 0.f;
#pragma unroll
        for (int k = 0; k < KS; ++k) {
            float d = (float)(k - PAD);
            w[k] = expf(-d * d * (1.0f / 50.0f));  // 2*sigma^2 = 50
            s += w[k];
        }
        float inv = 1.0f / s;
#pragma unroll
        for (int k = 0; k < KS; ++k) w[k] *= inv;
    }

    const int tid   = threadIdx.x;
    const int plane = blockIdx.z;
    const int x0    = blockIdx.x * TILE;
    const int y0    = blockIdx.y * TILE;

    const float* __restrict__ pin = in + (size_t)plane * (IMG_H * IMG_W);

    // ---- stage 1: global -> s_in (cols map to gx = x0-12+col) ----
    const bool x_interior = (blockIdx.x != 0) && (blockIdx.x != (IMG_W / TILE - 1));
    if (x_interior) {
        // float4 path: 84 rows x 22 float4 = 1848 vec loads; only gy may reflect
        for (int q = tid; q < LH * (SW_IN / 4); q += NTHREADS) {
            int ly  = q / (SW_IN / 4);
            int lx4 = q - ly * (SW_IN / 4);
            int col = lx4 << 2;
            int gy  = y0 + ly - PAD;
            gy = (gy < 0) ? -gy : ((gy >= IMG_H) ? (2 * IMG_H - 2 - gy) : gy);
            float4 f = *(const float4*)&pin[(size_t)gy * IMG_W + (x0 - 12) + col];
            *(float4*)&s_in[ly * SW_IN + col] = f;
        }
    } else {
        // scalar reflect path (x-border blocks only)
        for (int q = tid; q < LH * SW_IN; q += NTHREADS) {
            int ly = q / SW_IN;
            int lx = q - ly * SW_IN;
            int gy = y0 + ly - PAD;
            int gx = x0 + lx - 12;
            gy = (gy < 0) ? -gy : ((gy >= IMG_H) ? (2 * IMG_H - 2 - gy) : gy);
            gx = (gx < 0) ? -gx : ((gx >= IMG_W) ? (2 * IMG_W - 2 - gx) : gx);
            s_in[ly * SW_IN + lx] = pin[(size_t)gy * IMG_W + gx];
        }
    }
    __syncthreads();

    // ---- stage 2: horizontal 21-tap, 8 outputs/thread ----
    // output col lx+j reads input gx = x0+lx+j-10 -> s_in col = lx+j+2
    // window: v[t] = s_in[ly*SW_IN + lx + t], t=0..31; out_j = sum_k w[k]*v[2+j+k]
    for (int it = 0; it < 3; ++it) {
        int idx = tid + it * NTHREADS;
        if (idx < LH * (TILE / 8)) {          // 84 * 8 = 672 items
            int ly = idx >> 3;
            int lx = (idx & 7) << 3;
            const float4* rp = (const float4*)&s_in[ly * SW_IN + lx];
            float v[32];
#pragma unroll
            for (int t = 0; t < 8; ++t) {
                float4 f = rp[t];
                v[4 * t + 0] = f.x; v[4 * t + 1] = f.y;
                v[4 * t + 2] = f.z; v[4 * t + 3] = f.w;
            }
            float a[8] = {0, 0, 0, 0, 0, 0, 0, 0};
#pragma unroll
            for (int k = 0; k < KS; ++k) {
                float wk = w[k];
#pragma unroll
                for (int j = 0; j < 8; ++j) a[j] += wk * v[2 + j + k];
            }
            *(float4*)&s_h[ly * SW_H + lx]     = make_float4(a[0], a[1], a[2], a[3]);
            *(float4*)&s_h[ly * SW_H + lx + 4] = make_float4(a[4], a[5], a[6], a[7]);
        }
    }
    __syncthreads();

    // ---- stage 3: vertical 21-tap, wave = 16-row x 64-col strip, lane = x ----
    {
        const int wv = tid >> 6;          // wave 0..3
        const int x  = tid & 63;
        const int oy = wv << 4;           // 0,16,32,48

        float acc[16];
#pragma unroll
        for (int j = 0; j < 16; ++j) acc[j] = 0.f;

#pragma unroll
        for (int t = 0; t < 36; ++t) {    // rows oy..oy+35 (16 outs + 20 halo)
            float r = s_h[(oy + t) * SW_H + x];
#pragma unroll
            for (int j = 0; j < 16; ++j)
                if (j >= t - (KS - 1) && j <= t) acc[j] += w[t - j] * r;
        }

        float* __restrict__ pout = out + (size_t)plane * (IMG_H * IMG_W)
                                       + (size_t)(y0 + oy) * IMG_W + x0 + x;
#pragma unroll
        for (int j = 0; j < 16; ++j) pout[(size_t)j * IMG_W] = acc[j];
    }
}

extern "C" void kernel_launch(void* const* d_in, const int* in_sizes, int n_in,
                              void* d_out, int out_size, void* d_ws, size_t ws_size,
                              hipStream_t stream)
{
    const float* x = (const float*)d_in[0];
    float* out = (float*)d_out;

    dim3 grid(IMG_W / TILE, IMG_H / TILE, 96);   // 8 x 8 x (32*3) planes
    dim3 block(NTHREADS);
    gauss_blur_kernel<<<grid, block, 0, stream>>>(x, out);
}